// Round 9
// baseline (308.280 us; speedup 1.0000x reference)
//
#include <hip/hip_runtime.h>
#include <math.h>

#define BATCH 32
#define DIM   4096
#define CLEN  4096
#define HD    128
#define NKV   8
#define NHEAD 32
#define QKVN  6144          // (32 + 2*8) * 128
#define KVSTR (NKV * HD)    // 1024 floats between consecutive t rows
#define GBN   128           // N per gemm block
#define GKS   64            // K per gemm stage
#define GST   8             // stages per block (512 k)
#define XSTR  68            // padded LDS row stride (floats): 17 quads == 1 mod 8
#define NSEG  32            // k-partials: 8 block-ksegs x 4 wave-splits
#define NCH   16            // chunks per (b,g)
#define TC    256           // rows per wave-chunk
#define NSLOT 16            // one slot per chunk (halves merged in-kernel)
#define MNEG  -1.0e30f
#define SMASK -3.0e38f

// ---------------- helpers ----------------
template <int CTRL>
__device__ __forceinline__ float dpp_add(float x) {
  int y = __builtin_amdgcn_update_dpp(0, __float_as_int(x), CTRL, 0xF, 0xF, true);
  return x + __int_as_float(y);
}

// sum across the 32 lanes of each half-wave
__device__ __forceinline__ float half_reduce(float s) {
  s = dpp_add<0xB1>(s);    // quad_perm xor1
  s = dpp_add<0x4E>(s);    // quad_perm xor2
  s = dpp_add<0x124>(s);   // row_ror:4
  s = dpp_add<0x128>(s);   // row_ror:8
  s += __int_as_float(__builtin_amdgcn_ds_swizzle(__float_as_int(s), 0x401F)); // xor16
  return s;
}

__device__ __forceinline__ float xhalf32(float v, int lane) {
  return __int_as_float(__builtin_amdgcn_ds_bpermute((lane ^ 32) << 2, __float_as_int(v)));
}

// ---------------- skinny GEMM partial: part[seg][b][n] = sum_{k in seg} X[b][k]*W[n][k]
// LDS-BW-optimized: 8b x 8n register tile = 64 FMA per 64 B LDS (1 B/FMA, was 3).
// Tiles [row][k] k-major, row stride 68 floats (17 quads == 1 mod 8):
//   X read instr j: rows 4j..4j+3 -> 4 distinct bank-quads, 16-lane broadcast each.
//   W read instr i: rows 16i..16i+15 -> 2 rows/bank-quad (2-way = free).
// Wave w owns k-quads [4w,4w+4) per stage -> partial seg = blockIdx.y*4+w (NSEG=32).
__global__ __launch_bounds__(256)
void gemm_partial(const float* __restrict__ X, const float* __restrict__ W,
                  float* __restrict__ part, const int N) {
  __shared__ float xs[BATCH * XSTR];   // 8.7 KB
  __shared__ float wl[GBN * XSTR];     // 34.8 KB
  const int tid  = threadIdx.x;
  const int w    = tid >> 6;        // wave 0..3
  const int lane = tid & 63;
  const int bgrp = lane & 3;        // b = 4j + bgrp
  const int ngrp = lane >> 2;       // n = 16i + ngrp
  const int n0   = blockIdx.x * GBN;
  const int kb   = blockIdx.y * (GKS * GST);

  float acc[8][8] = {};

  for (int s = 0; s < GST; ++s) {
    const int k0 = kb + s * GKS;
    if (s) __syncthreads();           // previous compute done before LDS overwrite
    // ---- stage X: 512 quads, 2/thread (16 threads = 256 B contiguous) ----
    {
      int q = tid;
#pragma unroll
      for (int it = 0; it < 2; ++it, q += 256) {
        const int row = q >> 4, col = q & 15;
        *(float4*)&xs[row * XSTR + col * 4] =
            *(const float4*)(X + (size_t)row * DIM + k0 + col * 4);
      }
      // ---- stage W: 2048 quads, 8/thread ----
      q = tid;
#pragma unroll
      for (int it = 0; it < 8; ++it, q += 256) {
        const int row = q >> 4, col = q & 15;
        *(float4*)&wl[row * XSTR + col * 4] =
            *(const float4*)(W + (size_t)(n0 + row) * DIM + k0 + col * 4);
      }
    }
    __syncthreads();
    // ---- compute: wave w's 4 k-quads of this stage ----
#pragma unroll
    for (int kq = 0; kq < 4; ++kq) {
      const int ko = (w * 4 + kq) * 4;      // float offset within stage rows
      float4 xv[8], wv[8];
#pragma unroll
      for (int j = 0; j < 8; ++j)
        xv[j] = *(const float4*)&xs[(4 * j + bgrp) * XSTR + ko];
#pragma unroll
      for (int i = 0; i < 8; ++i)
        wv[i] = *(const float4*)&wl[(16 * i + ngrp) * XSTR + ko];
#pragma unroll
      for (int j = 0; j < 8; ++j)
#pragma unroll
        for (int i = 0; i < 8; ++i) {
          acc[j][i] = fmaf(xv[j].x, wv[i].x, acc[j][i]);
          acc[j][i] = fmaf(xv[j].y, wv[i].y, acc[j][i]);
          acc[j][i] = fmaf(xv[j].z, wv[i].z, acc[j][i]);
          acc[j][i] = fmaf(xv[j].w, wv[i].w, acc[j][i]);
        }
    }
  }

  // ---- write this wave's k-partial: seg = blockIdx.y*4 + w ----
  float* pb = part + (size_t)(blockIdx.y * 4 + w) * BATCH * N;
#pragma unroll
  for (int j = 0; j < 8; ++j) {
    const int b = 4 * j + bgrp;
#pragma unroll
    for (int i = 0; i < 8; ++i)
      pb[(size_t)b * N + n0 + 16 * i + ngrp] = acc[j][i];
  }
}

// ---------------- qkv combine + RoPE ----------------
__global__ __launch_bounds__(256)
void qkv_combine(const float* __restrict__ part, const int* __restrict__ ctxp,
                 float* __restrict__ qw, float* __restrict__ kn, float* __restrict__ vn) {
  const int idx = blockIdx.x * 256 + threadIdx.x;  // pair index: 32*3072
  const int b  = idx / (QKVN / 2);
  const int c  = idx % (QKVN / 2);
  const int n0 = c * 2;
  float v0 = 0.f, v1 = 0.f;
#pragma unroll 8
  for (int s = 0; s < NSEG; ++s) {
    const float2 pv = *(const float2*)(part + ((size_t)s * BATCH + b) * QKVN + n0);
    v0 += pv.x; v1 += pv.y;
  }
  const float pos = (float)ctxp[0];
  const float L2T_OVER_64 = 0.20762050593045952f;  // log2(10000)/64
  if (n0 < DIM) {
    const int i = (n0 & 127) >> 1;
    const float fr = exp2f(-(float)i * L2T_OVER_64);
    float sn, cs; sincosf(pos * fr, &sn, &cs);
    qw[(size_t)b * DIM + n0]     = v0 * cs - v1 * sn;
    qw[(size_t)b * DIM + n0 + 1] = v0 * sn + v1 * cs;
  } else if (n0 < DIM + NKV * HD) {
    const int nk = n0 - DIM;
    const int i = (nk & 127) >> 1;
    const float fr = exp2f(-(float)i * L2T_OVER_64);
    float sn, cs; sincosf(pos * fr, &sn, &cs);
    kn[(size_t)b * (NKV * HD) + nk]     = v0 * cs - v1 * sn;
    kn[(size_t)b * (NKV * HD) + nk + 1] = v0 * sn + v1 * cs;
  } else {
    const int nv = n0 - DIM - NKV * HD;
    vn[(size_t)b * (NKV * HD) + nv]     = v0;
    vn[(size_t)b * (NKV * HD) + nv + 1] = v1;
  }
}

// ---------------- flash-decode: ping-pong prefetch, 4 GQA heads per wave ----------------
__device__ __forceinline__ void load8(float4 kb[4], float4 vb[4],
    const float* __restrict__ ckb, const float* __restrict__ cvb,
    const float* __restrict__ knr, const float* __restrict__ vnr,
    const int t0, const int half, const int ctx, const bool edge) {
#pragma unroll
  for (int u = 0; u < 4; ++u) {
    const int tr = t0 + u * 2 + half;
    const float* kp = ckb + (size_t)tr * KVSTR;
    const float* vp = cvb + (size_t)tr * KVSTR;
    if (edge) {                       // wave-uniform branch
      if (tr == ctx) { kp = knr; vp = vnr; }
    }
    kb[u] = *(const float4*)kp;
    vb[u] = *(const float4*)vp;
  }
}

__device__ __forceinline__ void compute8(const float4 kb[4], const float4 vb[4],
    const float4 q[4], const int t0, const int half, const int ctx, const bool edge,
    float m[4], float l[4], float4 acc[4]) {
#pragma unroll
  for (int u = 0; u < 4; ++u) {
    float s[4];
#pragma unroll
    for (int hh = 0; hh < 4; ++hh) {
      float d = fmaf(kb[u].x, q[hh].x, kb[u].y * q[hh].y);
      d = fmaf(kb[u].z, q[hh].z, d);
      d = fmaf(kb[u].w, q[hh].w, d);
      s[hh] = half_reduce(d);
    }
    if (edge) {                       // wave-uniform branch
      const int tr = t0 + u * 2 + half;
      if (tr > ctx) { s[0] = SMASK; s[1] = SMASK; s[2] = SMASK; s[3] = SMASK; }
    }
    if ((s[0] > m[0]) | (s[1] > m[1]) | (s[2] > m[2]) | (s[3] > m[3])) {
#pragma unroll
      for (int hh = 0; hh < 4; ++hh) {
        const float mn = fmaxf(m[hh], s[hh]);
        const float rs = __expf(m[hh] - mn);
        l[hh] *= rs;
        acc[hh].x *= rs; acc[hh].y *= rs; acc[hh].z *= rs; acc[hh].w *= rs;
        m[hh] = mn;
      }
    }
#pragma unroll
    for (int hh = 0; hh < 4; ++hh) {
      const float p = __expf(s[hh] - m[hh]);
      l[hh] += p;
      acc[hh].x = fmaf(p, vb[u].x, acc[hh].x);
      acc[hh].y = fmaf(p, vb[u].y, acc[hh].y);
      acc[hh].z = fmaf(p, vb[u].z, acc[hh].z);
      acc[hh].w = fmaf(p, vb[u].w, acc[hh].w);
    }
  }
}

__global__ __launch_bounds__(256)
void attn_fd(const float* __restrict__ qw, const float* __restrict__ knew,
             const float* __restrict__ vnew, const float* __restrict__ ck,
             const float* __restrict__ cv, const int* __restrict__ ctxp,
             float* __restrict__ opart, float* __restrict__ mlp) {
  const int bg   = blockIdx.x;         // b*8 + g
  const int b = bg >> 3, g = bg & 7;
  const int wid  = threadIdx.x >> 6;
  const int lane = threadIdx.x & 63;
  const int half = lane >> 5;
  const int d4   = (lane & 31) << 2;
  const int cidx = blockIdx.y * 4 + wid;   // 0..15
  const int ctx  = ctxp[0];
  const int c0   = cidx * TC;

  const float sc = 0.08838834764831845f;   // 1/sqrt(128)
  float4 q[4];
#pragma unroll
  for (int hh = 0; hh < 4; ++hh) {
    q[hh] = *(const float4*)(qw + ((size_t)b * NHEAD + g * 4 + hh) * HD + d4);
    q[hh].x *= sc; q[hh].y *= sc; q[hh].z *= sc; q[hh].w *= sc;
  }
  const float* ckb = ck + ((size_t)b * CLEN * NKV + g) * HD + d4;
  const float* cvb = cv + ((size_t)b * CLEN * NKV + g) * HD + d4;
  const float* knr = knew + ((size_t)b * NKV + g) * HD + d4;
  const float* vnr = vnew + ((size_t)b * NKV + g) * HD + d4;

  float m[4] = {MNEG, MNEG, MNEG, MNEG};
  float l[4] = {0.f, 0.f, 0.f, 0.f};
  float4 acc[4] = {};

  float4 kA[4], vA[4], kB[4], vB[4];
  int t = c0;
  load8(kA, vA, ckb, cvb, knr, vnr, t, half, ctx, t + 8 > ctx);
  for (int it = 0; it < TC / 16; ++it) {
    const int tb = t + 8;
    load8(kB, vB, ckb, cvb, knr, vnr, tb, half, ctx, tb + 8 > ctx);
    compute8(kA, vA, q, t, half, ctx, t + 8 > ctx, m, l, acc);
    const int tn = t + 16;
    if (it + 1 < TC / 16)
      load8(kA, vA, ckb, cvb, knr, vnr, tn, half, ctx, tn + 8 > ctx);
    compute8(kB, vB, q, tb, half, ctx, tb + 8 > ctx, m, l, acc);
    t = tn;
  }

  // ---- merge the two half-wave states (ds_bpermute lane^32) ----
#pragma unroll
  for (int hh = 0; hh < 4; ++hh) {
    const float mo = xhalf32(m[hh], lane);
    const float lo = xhalf32(l[hh], lane);
    float4 ao;
    ao.x = xhalf32(acc[hh].x, lane); ao.y = xhalf32(acc[hh].y, lane);
    ao.z = xhalf32(acc[hh].z, lane); ao.w = xhalf32(acc[hh].w, lane);
    const float mc = fmaxf(m[hh], mo);
    const float wa = __expf(m[hh] - mc);
    const float wb = __expf(mo - mc);
    l[hh] = wa * l[hh] + wb * lo;
    acc[hh].x = wa * acc[hh].x + wb * ao.x;
    acc[hh].y = wa * acc[hh].y + wb * ao.y;
    acc[hh].z = wa * acc[hh].z + wb * ao.z;
    acc[hh].w = wa * acc[hh].w + wb * ao.w;
    m[hh] = mc;
  }
  if (half == 0) {
#pragma unroll
    for (int hh = 0; hh < 4; ++hh) {
      const int hid = b * NHEAD + g * 4 + hh;
      const size_t slot = (size_t)hid * NSLOT + cidx;
      *(float4*)(opart + slot * HD + d4) = acc[hh];
      if ((lane & 31) == 0) { mlp[slot * 2] = m[hh]; mlp[slot * 2 + 1] = l[hh]; }
    }
  }
}

// ---------------- flash combine ----------------
__global__ __launch_bounds__(128)
void attn_combine(const float* __restrict__ opart, const float* __restrict__ mlp,
                  float* __restrict__ ow) {
  const int p = blockIdx.x;      // 0..1023 = b*32 + g*4 + h
  const int d = threadIdx.x;     // 0..127
  float M = MNEG;
#pragma unroll
  for (int c = 0; c < NSLOT; ++c) M = fmaxf(M, mlp[((size_t)p * NSLOT + c) * 2]);
  float L = 0.f, O = 0.f;
#pragma unroll 8
  for (int c = 0; c < NSLOT; ++c) {
    const float mi = mlp[((size_t)p * NSLOT + c) * 2];
    const float w = __expf(mi - M);
    L += w * mlp[((size_t)p * NSLOT + c) * 2 + 1];
    O += w * opart[((size_t)p * NSLOT + c) * HD + d];
  }
  ow[(size_t)p * HD + d] = O / L;
}

// ---------------- sum GEMM partials ----------------
__global__ __launch_bounds__(256)
void sum_partials(const float* __restrict__ part, float* __restrict__ out,
                  const int total4, const int nseg, const int stride) {
  const int i = blockIdx.x * 256 + threadIdx.x;
  if (i >= total4) return;
  float4 s = make_float4(0.f, 0.f, 0.f, 0.f);
  for (int g = 0; g < nseg; ++g) {
    const float4 v = *(const float4*)(part + (size_t)g * stride + (size_t)i * 4);
    s.x += v.x; s.y += v.y; s.z += v.z; s.w += v.w;
  }
  *(float4*)(out + (size_t)i * 4) = s;
}

extern "C" void kernel_launch(void* const* d_in, const int* in_sizes, int n_in,
                              void* d_out, int out_size, void* d_ws, size_t ws_size,
                              hipStream_t stream) {
  const float* x    = (const float*)d_in[0];
  const float* ck   = (const float*)d_in[1];
  const float* cv   = (const float*)d_in[2];
  const float* wqkv = (const float*)d_in[3];
  const float* wo   = (const float*)d_in[4];
  const int*   ctx  = (const int*)d_in[5];

  float* ws    = (float*)d_ws;
  float* pqkv  = ws;                                        // 32*32*6144 (25.2 MB)
  float* qw    = pqkv + (size_t)NSEG * BATCH * QKVN;        // 32*4096
  float* kn    = qw + (size_t)BATCH * DIM;                  // 32*1024
  float* vn    = kn + (size_t)BATCH * NKV * HD;             // 32*1024
  float* opart = vn + (size_t)BATCH * NKV * HD;             // 1024*16*128
  float* mlp   = opart + (size_t)1024 * NSLOT * HD;         // 1024*16*2
  float* ow    = mlp + (size_t)1024 * NSLOT * 2;            // 32*4096
  float* pout  = pqkv;                                      // reuse (dead after qkv_combine)

  gemm_partial<<<dim3(QKVN / GBN, 8), 256, 0, stream>>>(x, wqkv, pqkv, QKVN);
  qkv_combine<<<dim3(BATCH * QKVN / 2 / 256), 256, 0, stream>>>(pqkv, ctx, qw, kn, vn);
  attn_fd<<<dim3(BATCH * NKV, NCH / 4), 256, 0, stream>>>(qw, kn, vn, ck, cv, ctx, opart, mlp);
  attn_combine<<<dim3(BATCH * NHEAD), HD, 0, stream>>>(opart, mlp, ow);
  gemm_partial<<<dim3(DIM / GBN, 8), 256, 0, stream>>>(ow, wo, pout, DIM);
  sum_partials<<<dim3((BATCH * DIM / 4 + 255) / 256), 256, 0, stream>>>(
      pout, (float*)d_out, BATCH * DIM / 4, NSEG, BATCH * DIM);
}